// Round 2
// baseline (443.697 us; speedup 1.0000x reference)
//
#include <hip/hip_runtime.h>
#include <math.h>

#define DMODEL 768
#define NHEAD 12
#define DKDIM 64
#define BB 2
#define SS 2048
#define MROWS (BB * SS)          // 4096
#define WELEM (DMODEL * DMODEL)  // 589824
#define KCHUNK (SS / 2)          // 1024 per in-block K-split group
#define MWORDS (SS / 64)         // 32 u64 mask words per row

typedef unsigned short bf16_t;
typedef __attribute__((ext_vector_type(8))) short s8;   // 8 bf16 = 4 VGPRs (MFMA A/B frag)
typedef __attribute__((ext_vector_type(4))) float f4;   // MFMA C/D frag

#define MFMA(a, b, c) __builtin_amdgcn_mfma_f32_16x16x32_bf16((a), (b), (c), 0, 0, 0)

__device__ __forceinline__ bf16_t f2bf(float f) {   // round-to-nearest-even
    unsigned u = __float_as_uint(f);
    u += 0x7fffu + ((u >> 16) & 1u);
    return (bf16_t)(u >> 16);
}
__device__ __forceinline__ unsigned pack2(float a, float b) {
    return (unsigned)f2bf(a) | ((unsigned)f2bf(b) << 16);
}
__device__ __forceinline__ s8 ldfrag(const bf16_t* p) {
    union { uint4 u; s8 s; } x;
    x.u = *(const uint4*)p;
    return x.s;
}

// stage 16 consecutive elements -> 2 x uint4 of packed bf16
__device__ __forceinline__ void ld_stage(const bf16_t* p, uint4& u0, uint4& u1) {
    u0 = *(const uint4*)p;
    u1 = *(const uint4*)(p + 8);
}
__device__ __forceinline__ void ld_stage(const float* p, uint4& u0, uint4& u1) {
    const float4 f0 = *(const float4*)p;
    const float4 f1 = *(const float4*)(p + 4);
    const float4 f2 = *(const float4*)(p + 8);
    const float4 f3 = *(const float4*)(p + 12);
    u0.x = pack2(f0.x, f0.y); u0.y = pack2(f0.z, f0.w);
    u0.z = pack2(f1.x, f1.y); u0.w = pack2(f1.z, f1.w);
    u1.x = pack2(f2.x, f2.y); u1.y = pack2(f2.z, f2.w);
    u1.z = pack2(f3.x, f3.y); u1.w = pack2(f3.z, f3.w);
}

// ---------------------------------------------------------------------------
// Weight prepass: fp32 -> bf16, 4 matrices of 768x768. grid (576, 4), 256 thr.
// ---------------------------------------------------------------------------
__global__ void cvt_weights(const float* __restrict__ W0, const float* __restrict__ W1,
                            const float* __restrict__ W2, const float* __restrict__ W3,
                            bf16_t* __restrict__ dst)
{
    const float* src = (blockIdx.y == 0) ? W0 : (blockIdx.y == 1) ? W1
                     : (blockIdx.y == 2) ? W2 : W3;
    bf16_t* d = dst + (size_t)blockIdx.y * WELEM;
    const int i = (blockIdx.x * 256 + threadIdx.x) * 4;
    const float4 v = *(const float4*)(src + i);
    ushort4 h;
    h.x = f2bf(v.x); h.y = f2bf(v.y); h.z = f2bf(v.z); h.w = f2bf(v.w);
    *(ushort4*)(d + i) = h;
}

// ---------------------------------------------------------------------------
// Mask prepass: int32 [B,S,S] -> bit-packed u64 words (1 MB total, L2-resident).
// One wave's ballot produces one u64: bit j of word g == mask[g*64 + j] != 0.
// ---------------------------------------------------------------------------
__global__ __launch_bounds__(256) void mask_to_bits(
    const int* __restrict__ mask, unsigned long long* __restrict__ mbits)
{
    const size_t gid = (size_t)blockIdx.x * 256 + threadIdx.x;
    const int m = mask[gid];
    const unsigned long long bal = __ballot(m != 0);
    if ((threadIdx.x & 63) == 0) mbits[gid >> 6] = bal;
}

// ---------------------------------------------------------------------------
// LDS-staged MFMA GEMM (m93-style): C[M,768] = (A[M,768] @ W[768,768]^T + bias)*sc.
// 128x128 block tile, BK=32, 256 thr = 4 waves in 2x2. blockIdx.z selects one
// of 3 fused problem instances. sc folds 1/sqrt(d_k) into the Q projection.
// ---------------------------------------------------------------------------
template<typename TA, typename TO>
__global__ __launch_bounds__(256) void gemm_tiled(
    const TA* __restrict__ A0, const TA* __restrict__ A1, const TA* __restrict__ A2,
    const bf16_t* __restrict__ W0, const bf16_t* __restrict__ W1, const bf16_t* __restrict__ W2,
    const float* __restrict__ bias0, const float* __restrict__ bias1, const float* __restrict__ bias2,
    TO* __restrict__ C0, TO* __restrict__ C1, TO* __restrict__ C2,
    float sc0, float sc1, float sc2)
{
    __shared__ uint4 As4[128 * 4];   // 128 rows x 4 swizzled 16B blocks (8 KB)
    __shared__ uint4 Bs4[128 * 4];

    const int z = blockIdx.z;
    const TA*     A    = (z == 0) ? A0 : (z == 1) ? A1 : A2;
    const bf16_t* W    = (z == 0) ? W0 : (z == 1) ? W1 : W2;
    const float*  bias = (z == 0) ? bias0 : (z == 1) ? bias1 : bias2;
    TO*           C    = (z == 0) ? C0 : (z == 1) ? C1 : C2;
    const float   sc   = (z == 0) ? sc0 : (z == 1) ? sc1 : sc2;

    const int tid  = threadIdx.x;
    const int lane = tid & 63;
    const int w    = tid >> 6;
    const int wm   = w & 1;
    const int wn   = w >> 1;
    const int l15  = lane & 15;
    const int quad = lane >> 4;
    const int m0   = blockIdx.y * 128;
    const int n0   = blockIdx.x * 128;

    const int srow  = tid >> 1;   // 0..127 staging row
    const int shalf = tid & 1;    // which 16-element k-half
    const int sw    = srow & 3;

    const TA*     aptr = A + (size_t)(m0 + srow) * DMODEL + shalf * 16;
    const bf16_t* wptr = W + (size_t)(n0 + srow) * DMODEL + shalf * 16;

    f4 acc[4][4];
    #pragma unroll
    for (int i = 0; i < 4; i++)
        #pragma unroll
        for (int j = 0; j < 4; j++)
            acc[i][j] = (f4){0.f, 0.f, 0.f, 0.f};

    for (int k0 = 0; k0 < DMODEL; k0 += 32) {
        uint4 au0, au1, bu0, bu1;
        ld_stage(aptr + k0, au0, au1);
        ld_stage(wptr + k0, bu0, bu1);
        __syncthreads();   // previous iteration's fragment reads complete
        As4[srow * 4 + ((shalf * 2 + 0) ^ sw)] = au0;
        As4[srow * 4 + ((shalf * 2 + 1) ^ sw)] = au1;
        Bs4[srow * 4 + ((shalf * 2 + 0) ^ sw)] = bu0;
        Bs4[srow * 4 + ((shalf * 2 + 1) ^ sw)] = bu1;
        __syncthreads();

        s8 af[4], bf[4];
        #pragma unroll
        for (int t = 0; t < 4; t++) {
            const int ar = wm * 64 + t * 16 + l15;
            const int br = wn * 64 + t * 16 + l15;
            union { uint4 u; s8 s; } xa, xb;
            xa.u = As4[ar * 4 + (quad ^ (ar & 3))];
            xb.u = Bs4[br * 4 + (quad ^ (br & 3))];
            af[t] = xa.s;
            bf[t] = xb.s;
        }
        #pragma unroll
        for (int mt = 0; mt < 4; mt++)
            #pragma unroll
            for (int nt = 0; nt < 4; nt++)
                acc[mt][nt] = MFMA(af[mt], bf[nt], acc[mt][nt]);
    }

    // epilogue: row = m0+64wm+16mt+4quad+reg, col = n0+64wn+16nt+l15
    #pragma unroll
    for (int mt = 0; mt < 4; mt++) {
        #pragma unroll
        for (int nt = 0; nt < 4; nt++) {
            const int col = n0 + wn * 64 + nt * 16 + l15;
            const float bb = bias[col];
            #pragma unroll
            for (int reg = 0; reg < 4; reg++) {
                const int row = m0 + wm * 64 + mt * 16 + quad * 4 + reg;
                const float val = (acc[mt][nt][reg] + bb) * sc;
                TO* dst = C + (size_t)row * DMODEL + col;
                if constexpr (sizeof(TO) == 2) *dst = f2bf(val);
                else                           *dst = val;
            }
        }
    }
}

// ---------------------------------------------------------------------------
// MFMA flash attention — IN-BLOCK K-split x2.
// grid (S/64, H, B), 512 thr = 8 waves. Waves 0-3 (ws=0) process K [0,1024),
// waves 4-7 (ws=1) process K [1024,2048), same 64 q-rows (wq = w&3 picks the
// 16-row sub-tile). Each group has its own LDS V/P buffers; partials merge
// through LDS at the end (m/l exchange + scaled-O add). vs the round-1 global
// K-split this keeps occupancy at 24 waves/CU with ZERO extra HBM traffic
// (round 1: FETCH 70->128 MB, WRITE 6->180 MB, dur 173->202 us — reverted).
// Mask is bit-packed (4 x u64 loads/iter from a 1 MB L2-resident buffer).
// Next V tile prefetched a full iteration ahead. Q pre-scaled by 1/8.
// ---------------------------------------------------------------------------
__global__ __launch_bounds__(512, 6) void attn_mfma(
    const bf16_t* __restrict__ Q, const bf16_t* __restrict__ K,
    const bf16_t* __restrict__ V, const unsigned long long* __restrict__ mbits,
    bf16_t* __restrict__ O)
{
    __shared__ unsigned Vs[2][64][36];    // per-group V tile: Vs[g][d][kpair]
    __shared__ unsigned Ps[8][16][36];    // per-wave P, A-layout packed pairs
    __shared__ float    Msh[8][16], Lsh[8][16];

    const int tid  = threadIdx.x;
    const int lane = tid & 63;
    const int w    = tid >> 6;            // 0..7
    const int wq   = w & 3;               // q sub-tile
    const int ws   = w >> 2;              // K-split group
    const int l15  = lane & 15;
    const int quad = lane >> 4;
    const int q0   = blockIdx.x * 64;
    const int h    = blockIdx.y;
    const int b    = blockIdx.z;
    const int ks   = ws * KCHUNK;
    const size_t base = ((size_t)b * SS) * DMODEL + (size_t)h * DKDIM;

    const bf16_t* qrow = Q + base + (size_t)(q0 + wq * 16 + l15) * DMODEL + quad * 8;
    const s8 qf0 = ldfrag(qrow);
    const s8 qf1 = ldfrag(qrow + 32);

    f4 oacc[4];
    float m_run[4], l_run[4];
    #pragma unroll
    for (int i = 0; i < 4; i++) {
        oacc[i] = (f4){0.f, 0.f, 0.f, 0.f};
        m_run[i] = -3.0e30f; l_run[i] = 0.0f;
    }

    const int kp  = tid & 31;             // V staging: same within each group
    const int oct = (tid >> 5) & 7;
    const bf16_t* vbase = V + base + (size_t)(2 * kp) * DMODEL + oct * 8;

    // bit-mask word base for this thread's 4 q-rows
    const unsigned long long* mbase =
        mbits + ((size_t)b * SS + (q0 + wq * 16 + quad * 4)) * MWORDS;

    // preload first V tile of this group's chunk
    uint4 va = *(const uint4*)(vbase + (size_t)ks * DMODEL);
    uint4 vb = *(const uint4*)(vbase + (size_t)ks * DMODEL + DMODEL);

    for (int k0 = ks; k0 < ks + KCHUNK; k0 += 64) {
        __syncthreads();   // previous iteration's PV reads of Vs/Ps complete
        {
            const unsigned short* pa = (const unsigned short*)&va;
            const unsigned short* pb = (const unsigned short*)&vb;
            #pragma unroll
            for (int i = 0; i < 8; i++)
                Vs[ws][oct * 8 + i][kp] = (unsigned)pa[i] | ((unsigned)pb[i] << 16);
        }
        // prefetch NEXT V tile: a full iteration of QK^T+softmax+PV covers it
        if (k0 + 64 < ks + KCHUNK) {
            va = *(const uint4*)(vbase + (size_t)(k0 + 64) * DMODEL);
            vb = *(const uint4*)(vbase + (size_t)(k0 + 64) * DMODEL + DMODEL);
        }
        // current mask words (4 q-rows x 64 k) — issue before QK^T MFMAs
        unsigned long long mw[4];
        #pragma unroll
        for (int reg = 0; reg < 4; reg++)
            mw[reg] = mbase[(size_t)reg * MWORDS + (k0 >> 6)];

        f4 sacc[4];
        #pragma unroll
        for (int nt = 0; nt < 4; nt++) {
            const bf16_t* krow = K + base + (size_t)(k0 + nt * 16 + l15) * DMODEL + quad * 8;
            f4 zz2 = {0.f, 0.f, 0.f, 0.f};
            zz2 = MFMA(qf0, ldfrag(krow), zz2);
            zz2 = MFMA(qf1, ldfrag(krow + 32), zz2);
            sacc[nt] = zz2;
        }

        float p[4][4];
        #pragma unroll
        for (int reg = 0; reg < 4; reg++) {
            // bit (nt*16 + l15) of mw[reg] masks column k0+nt*16+l15
            const unsigned mlo = ((unsigned)mw[reg]) >> l15;
            const unsigned mhi = ((unsigned)(mw[reg] >> 32)) >> l15;
            float sv[4];
            sv[0] = (mlo & 1u)       ? sacc[0][reg] : -1.0e9f;
            sv[1] = (mlo & 0x10000u) ? sacc[1][reg] : -1.0e9f;
            sv[2] = (mhi & 1u)       ? sacc[2][reg] : -1.0e9f;
            sv[3] = (mhi & 0x10000u) ? sacc[3][reg] : -1.0e9f;

            float mx = fmaxf(fmaxf(sv[0], sv[1]), fmaxf(sv[2], sv[3]));
            mx = fmaxf(mx, __shfl_xor(mx, 1, 16));
            mx = fmaxf(mx, __shfl_xor(mx, 2, 16));
            mx = fmaxf(mx, __shfl_xor(mx, 4, 16));
            mx = fmaxf(mx, __shfl_xor(mx, 8, 16));

            const float m_new = fmaxf(m_run[reg], mx);
            const float alpha = __expf(m_run[reg] - m_new);
            float rs = 0.f;
            #pragma unroll
            for (int nt = 0; nt < 4; nt++) {
                p[reg][nt] = __expf(sv[nt] - m_new);
                rs += p[reg][nt];
            }
            rs += __shfl_xor(rs, 1, 16);
            rs += __shfl_xor(rs, 2, 16);
            rs += __shfl_xor(rs, 4, 16);
            rs += __shfl_xor(rs, 8, 16);

            l_run[reg] = l_run[reg] * alpha + rs;
            m_run[reg] = m_new;
            #pragma unroll
            for (int dt = 0; dt < 4; dt++) oacc[dt][reg] *= alpha;
        }

        #pragma unroll
        for (int reg = 0; reg < 4; reg++) {
            #pragma unroll
            for (int nt = 0; nt < 4; nt++) {
                const float mine  = p[reg][nt];
                const float other = __shfl_xor(mine, 1, 16);
                if ((lane & 1) == 0)
                    Ps[w][quad * 4 + reg][nt * 8 + (l15 >> 1)] = pack2(mine, other);
            }
        }
        __syncthreads();

        #pragma unroll
        for (int kt = 0; kt < 2; kt++) {
            union { uint4 u; s8 s; } pf;
            pf.u = *(const uint4*)&Ps[w][l15][kt * 16 + quad * 4];
            #pragma unroll
            for (int dt = 0; dt < 4; dt++) {
                union { uint4 u; s8 s; } vf;
                vf.u = *(const uint4*)&Vs[ws][dt * 16 + l15][kt * 16 + quad * 4];
                oacc[dt] = MFMA(pf.s, vf.s, oacc[dt]);
            }
        }
    }

    // ---- merge the two K-half partials through LDS ----
    // exchange (m, l): values are uniform over l15 within a (quad, reg) row
    if (l15 == 0) {
        #pragma unroll
        for (int reg = 0; reg < 4; reg++) {
            Msh[w][quad * 4 + reg] = m_run[reg];
            Lsh[w][quad * 4 + reg] = l_run[reg];
        }
    }
    __syncthreads();   // Msh/Lsh visible; all Ps/Vs reads complete (alias below)

    float scale[4];
    #pragma unroll
    for (int reg = 0; reg < 4; reg++) {
        const float m_o = Msh[w ^ 4][quad * 4 + reg];
        const float l_o = Lsh[w ^ 4][quad * 4 + reg];
        const float m_t = fmaxf(m_run[reg], m_o);
        const float w_s = __expf(m_run[reg] - m_t);
        const float w_o = __expf(m_o - m_t);
        const float l_t = l_run[reg] * w_s + l_o * w_o;   // same value on both waves
        scale[reg] = w_s / l_t;
    }
    #pragma unroll
    for (int dt = 0; dt < 4; dt++)
        #pragma unroll
        for (int reg = 0; reg < 4; reg++)
            oacc[dt][reg] *= scale[reg];

    // group 1 deposits its scaled O into LDS (aliases Ps; stride 66 -> 2-way max)
    float (*Osh)[16][66] = (float (*)[16][66])Ps;
    if (ws == 1) {
        #pragma unroll
        for (int dt = 0; dt < 4; dt++)
            #pragma unroll
            for (int reg = 0; reg < 4; reg++)
                Osh[wq][quad * 4 + reg][dt * 16 + l15] = oacc[dt][reg];
    }
    __syncthreads();

    if (ws == 0) {
        #pragma unroll
        for (int reg = 0; reg < 4; reg++) {
            const size_t row = q0 + wq * 16 + quad * 4 + reg;
            #pragma unroll
            for (int dt = 0; dt < 4; dt++) {
                const float val = oacc[dt][reg] + Osh[wq][quad * 4 + reg][dt * 16 + l15];
                O[base + row * DMODEL + dt * 16 + l15] = f2bf(val);
            }
        }
    }
}

// ---------------------------------------------------------------------------
extern "C" void kernel_launch(void* const* d_in, const int* in_sizes, int n_in,
                              void* d_out, int out_size, void* d_ws, size_t ws_size,
                              hipStream_t stream)
{
    const float* q    = (const float*)d_in[0];
    const float* k    = (const float*)d_in[1];
    const float* v    = (const float*)d_in[2];
    const int*   mask = (const int*)  d_in[3];
    const float* Wq   = (const float*)d_in[4];
    const float* bq   = (const float*)d_in[5];
    const float* Wk   = (const float*)d_in[6];
    const float* bk   = (const float*)d_in[7];
    const float* Wv   = (const float*)d_in[8];
    const float* bv   = (const float*)d_in[9];
    const float* Wo   = (const float*)d_in[10];
    const float* bo   = (const float*)d_in[11];
    float* out = (float*)d_out;

    // workspace: 4 bf16 planes (25.2 MB) + 4 bf16 weights (4.7 MB) + mbits (1 MB)
    bf16_t* wsb = (bf16_t*)d_ws;
    const size_t plane = (size_t)MROWS * DMODEL;   // 3,145,728
    bf16_t* Qp  = wsb;
    bf16_t* Kp  = wsb + plane;
    bf16_t* Vp  = wsb + 2 * plane;
    bf16_t* Ctx = wsb + 3 * plane;
    bf16_t* Wqb = wsb + 4 * plane;
    bf16_t* Wkb = Wqb + WELEM;
    bf16_t* Wvb = Wkb + WELEM;
    bf16_t* Wob = Wvb + WELEM;
    unsigned long long* mbits = (unsigned long long*)(Wob + WELEM);

    cvt_weights<<<dim3(WELEM / 1024, 4), 256, 0, stream>>>(Wq, Wk, Wv, Wo, Wqb);
    mask_to_bits<<<dim3((BB * SS * SS) / 256), 256, 0, stream>>>(mask, mbits);

    // fused Q/K/V projections (Q pre-scaled by 1/8): grid (6, 32, 3)
    gemm_tiled<float, bf16_t><<<dim3(DMODEL / 128, MROWS / 128, 3), 256, 0, stream>>>(
        q, k, v, Wqb, Wkb, Wvb, bq, bk, bv, Qp, Kp, Vp, 0.125f, 1.0f, 1.0f);

    // in-block K-split flash attention: grid (32, 12, 2), 512 thr
    attn_mfma<<<dim3(SS / 64, NHEAD, BB), 512, 0, stream>>>(Qp, Kp, Vp, mbits, Ctx);

    // output projection: grid (6, 32, 1)
    gemm_tiled<bf16_t, float><<<dim3(DMODEL / 128, MROWS / 128, 1), 256, 0, stream>>>(
        Ctx, Ctx, Ctx, Wob, Wob, Wob, bo, bo, bo, out, out, out, 1.0f, 1.0f, 1.0f);
}

// Round 3
// 374.396 us; speedup vs baseline: 1.1851x; 1.1851x over previous
//
#include <hip/hip_runtime.h>
#include <math.h>

#define DMODEL 768
#define NHEAD 12
#define DKDIM 64
#define BB 2
#define SS 2048
#define MROWS (BB * SS)          // 4096
#define WELEM (DMODEL * DMODEL)  // 589824
#define KCHUNK (SS / 2)          // 1024 per in-block K-split group
#define MWORDS (SS / 64)         // 32 u64 mask words per row

typedef unsigned short bf16_t;
typedef __attribute__((ext_vector_type(8))) short s8;   // 8 bf16 = 4 VGPRs (MFMA A/B frag)
typedef __attribute__((ext_vector_type(4))) float f4;   // MFMA C/D frag

#define MFMA(a, b, c) __builtin_amdgcn_mfma_f32_16x16x32_bf16((a), (b), (c), 0, 0, 0)

__device__ __forceinline__ bf16_t f2bf(float f) {   // round-to-nearest-even
    unsigned u = __float_as_uint(f);
    u += 0x7fffu + ((u >> 16) & 1u);
    return (bf16_t)(u >> 16);
}
__device__ __forceinline__ unsigned pack2(float a, float b) {
    return (unsigned)f2bf(a) | ((unsigned)f2bf(b) << 16);
}
__device__ __forceinline__ s8 ldfrag(const bf16_t* p) {
    union { uint4 u; s8 s; } x;
    x.u = *(const uint4*)p;
    return x.s;
}

// stage 16 consecutive elements -> 2 x uint4 of packed bf16
__device__ __forceinline__ void ld_stage(const bf16_t* p, uint4& u0, uint4& u1) {
    u0 = *(const uint4*)p;
    u1 = *(const uint4*)(p + 8);
}
__device__ __forceinline__ void ld_stage(const float* p, uint4& u0, uint4& u1) {
    const float4 f0 = *(const float4*)p;
    const float4 f1 = *(const float4*)(p + 4);
    const float4 f2 = *(const float4*)(p + 8);
    const float4 f3 = *(const float4*)(p + 12);
    u0.x = pack2(f0.x, f0.y); u0.y = pack2(f0.z, f0.w);
    u0.z = pack2(f1.x, f1.y); u0.w = pack2(f1.z, f1.w);
    u1.x = pack2(f2.x, f2.y); u1.y = pack2(f2.z, f2.w);
    u1.z = pack2(f3.x, f3.y); u1.w = pack2(f3.z, f3.w);
}

// ---------------------------------------------------------------------------
// Weight prepass: fp32 -> bf16, 4 matrices of 768x768. grid (576, 4), 256 thr.
// ---------------------------------------------------------------------------
__global__ void cvt_weights(const float* __restrict__ W0, const float* __restrict__ W1,
                            const float* __restrict__ W2, const float* __restrict__ W3,
                            bf16_t* __restrict__ dst)
{
    const float* src = (blockIdx.y == 0) ? W0 : (blockIdx.y == 1) ? W1
                     : (blockIdx.y == 2) ? W2 : W3;
    bf16_t* d = dst + (size_t)blockIdx.y * WELEM;
    const int i = (blockIdx.x * 256 + threadIdx.x) * 4;
    const float4 v = *(const float4*)(src + i);
    ushort4 h;
    h.x = f2bf(v.x); h.y = f2bf(v.y); h.z = f2bf(v.z); h.w = f2bf(v.w);
    *(ushort4*)(d + i) = h;
}

// ---------------------------------------------------------------------------
// Mask prepass: int32 [B,S,S] -> bit-packed u64 words (1 MB total, L2-resident).
// One wave's ballot produces one u64: bit j of word g == mask[g*64 + j] != 0.
// ---------------------------------------------------------------------------
__global__ __launch_bounds__(256) void mask_to_bits(
    const int* __restrict__ mask, unsigned long long* __restrict__ mbits)
{
    const size_t gid = (size_t)blockIdx.x * 256 + threadIdx.x;
    const int m = mask[gid];
    const unsigned long long bal = __ballot(m != 0);
    if ((threadIdx.x & 63) == 0) mbits[gid >> 6] = bal;
}

// ---------------------------------------------------------------------------
// LDS-staged MFMA GEMM (m93-style): C[M,768] = (A[M,768] @ W[768,768]^T + bias)*sc.
// 128x128 block tile, BK=32, 256 thr = 4 waves in 2x2. blockIdx.z selects one
// of 3 fused problem instances. sc folds 1/sqrt(d_k) into the Q projection.
// ---------------------------------------------------------------------------
template<typename TA, typename TO>
__global__ __launch_bounds__(256) void gemm_tiled(
    const TA* __restrict__ A0, const TA* __restrict__ A1, const TA* __restrict__ A2,
    const bf16_t* __restrict__ W0, const bf16_t* __restrict__ W1, const bf16_t* __restrict__ W2,
    const float* __restrict__ bias0, const float* __restrict__ bias1, const float* __restrict__ bias2,
    TO* __restrict__ C0, TO* __restrict__ C1, TO* __restrict__ C2,
    float sc0, float sc1, float sc2)
{
    __shared__ uint4 As4[128 * 4];   // 128 rows x 4 swizzled 16B blocks (8 KB)
    __shared__ uint4 Bs4[128 * 4];

    const int z = blockIdx.z;
    const TA*     A    = (z == 0) ? A0 : (z == 1) ? A1 : A2;
    const bf16_t* W    = (z == 0) ? W0 : (z == 1) ? W1 : W2;
    const float*  bias = (z == 0) ? bias0 : (z == 1) ? bias1 : bias2;
    TO*           C    = (z == 0) ? C0 : (z == 1) ? C1 : C2;
    const float   sc   = (z == 0) ? sc0 : (z == 1) ? sc1 : sc2;

    const int tid  = threadIdx.x;
    const int lane = tid & 63;
    const int w    = tid >> 6;
    const int wm   = w & 1;
    const int wn   = w >> 1;
    const int l15  = lane & 15;
    const int quad = lane >> 4;
    const int m0   = blockIdx.y * 128;
    const int n0   = blockIdx.x * 128;

    const int srow  = tid >> 1;   // 0..127 staging row
    const int shalf = tid & 1;    // which 16-element k-half
    const int sw    = srow & 3;

    const TA*     aptr = A + (size_t)(m0 + srow) * DMODEL + shalf * 16;
    const bf16_t* wptr = W + (size_t)(n0 + srow) * DMODEL + shalf * 16;

    f4 acc[4][4];
    #pragma unroll
    for (int i = 0; i < 4; i++)
        #pragma unroll
        for (int j = 0; j < 4; j++)
            acc[i][j] = (f4){0.f, 0.f, 0.f, 0.f};

    for (int k0 = 0; k0 < DMODEL; k0 += 32) {
        uint4 au0, au1, bu0, bu1;
        ld_stage(aptr + k0, au0, au1);
        ld_stage(wptr + k0, bu0, bu1);
        __syncthreads();   // previous iteration's fragment reads complete
        As4[srow * 4 + ((shalf * 2 + 0) ^ sw)] = au0;
        As4[srow * 4 + ((shalf * 2 + 1) ^ sw)] = au1;
        Bs4[srow * 4 + ((shalf * 2 + 0) ^ sw)] = bu0;
        Bs4[srow * 4 + ((shalf * 2 + 1) ^ sw)] = bu1;
        __syncthreads();

        s8 af[4], bf[4];
        #pragma unroll
        for (int t = 0; t < 4; t++) {
            const int ar = wm * 64 + t * 16 + l15;
            const int br = wn * 64 + t * 16 + l15;
            union { uint4 u; s8 s; } xa, xb;
            xa.u = As4[ar * 4 + (quad ^ (ar & 3))];
            xb.u = Bs4[br * 4 + (quad ^ (br & 3))];
            af[t] = xa.s;
            bf[t] = xb.s;
        }
        #pragma unroll
        for (int mt = 0; mt < 4; mt++)
            #pragma unroll
            for (int nt = 0; nt < 4; nt++)
                acc[mt][nt] = MFMA(af[mt], bf[nt], acc[mt][nt]);
    }

    // epilogue: row = m0+64wm+16mt+4quad+reg, col = n0+64wn+16nt+l15
    #pragma unroll
    for (int mt = 0; mt < 4; mt++) {
        #pragma unroll
        for (int nt = 0; nt < 4; nt++) {
            const int col = n0 + wn * 64 + nt * 16 + l15;
            const float bb = bias[col];
            #pragma unroll
            for (int reg = 0; reg < 4; reg++) {
                const int row = m0 + wm * 64 + mt * 16 + quad * 4 + reg;
                const float val = (acc[mt][nt][reg] + bb) * sc;
                TO* dst = C + (size_t)row * DMODEL + col;
                if constexpr (sizeof(TO) == 2) *dst = f2bf(val);
                else                           *dst = val;
            }
        }
    }
}

// ---------------------------------------------------------------------------
// MFMA flash attention — IN-BLOCK K-split x2.
// grid (S/64, H, B), 512 thr = 8 waves. Waves 0-3 (ws=0) process K [0,1024),
// waves 4-7 (ws=1) process K [1024,2048), same 64 q-rows. Partials merge
// through LDS (m/l exchange + scaled-O add): zero extra HBM traffic.
//
// NOTE on __launch_bounds__: rounds 1-2 used (.., 6) to force occupancy; the
// register cap made the compiler spill (VGPR_Count 56->40, WRITE_SIZE
// 6 MB -> 360 MB of scratch round-trips, dur 173->258 us). Plain (512):
// let regalloc pick ~80-96 VGPRs, no spill; occupancy lands at 16-24
// waves/CU naturally (vs 12 in the unsplit kernel).
// Ps-write folded into the per-reg softmax loop so only p[4] is live
// (round-2 kept p[4][4] live across the whole softmax).
// Mask is bit-packed (4 x u64 loads/iter from a 1 MB L2-resident buffer).
// Next V tile prefetched a full iteration ahead. Q pre-scaled by 1/8.
// ---------------------------------------------------------------------------
__global__ __launch_bounds__(512) void attn_mfma(
    const bf16_t* __restrict__ Q, const bf16_t* __restrict__ K,
    const bf16_t* __restrict__ V, const unsigned long long* __restrict__ mbits,
    bf16_t* __restrict__ O)
{
    __shared__ unsigned Vs[2][64][36];    // per-group V tile: Vs[g][d][kpair]
    __shared__ unsigned Ps[8][16][36];    // per-wave P, A-layout packed pairs
    __shared__ float    Msh[8][16], Lsh[8][16];

    const int tid  = threadIdx.x;
    const int lane = tid & 63;
    const int w    = tid >> 6;            // 0..7
    const int wq   = w & 3;               // q sub-tile
    const int ws   = w >> 2;              // K-split group
    const int l15  = lane & 15;
    const int quad = lane >> 4;
    const int q0   = blockIdx.x * 64;
    const int h    = blockIdx.y;
    const int b    = blockIdx.z;
    const int ks   = ws * KCHUNK;
    const size_t base = ((size_t)b * SS) * DMODEL + (size_t)h * DKDIM;

    const bf16_t* qrow = Q + base + (size_t)(q0 + wq * 16 + l15) * DMODEL + quad * 8;
    const s8 qf0 = ldfrag(qrow);
    const s8 qf1 = ldfrag(qrow + 32);

    f4 oacc[4];
    float m_run[4], l_run[4];
    #pragma unroll
    for (int i = 0; i < 4; i++) {
        oacc[i] = (f4){0.f, 0.f, 0.f, 0.f};
        m_run[i] = -3.0e30f; l_run[i] = 0.0f;
    }

    const int kp  = tid & 31;             // V staging: same within each group
    const int oct = (tid >> 5) & 7;
    const bf16_t* vbase = V + base + (size_t)(2 * kp) * DMODEL + oct * 8;

    // bit-mask word base for this thread's 4 q-rows
    const unsigned long long* mbase =
        mbits + ((size_t)b * SS + (q0 + wq * 16 + quad * 4)) * MWORDS;

    // preload first V tile of this group's chunk
    uint4 va = *(const uint4*)(vbase + (size_t)ks * DMODEL);
    uint4 vb = *(const uint4*)(vbase + (size_t)ks * DMODEL + DMODEL);

    for (int k0 = ks; k0 < ks + KCHUNK; k0 += 64) {
        __syncthreads();   // previous iteration's PV reads of Vs/Ps complete
        {
            const unsigned short* pa = (const unsigned short*)&va;
            const unsigned short* pb = (const unsigned short*)&vb;
            #pragma unroll
            for (int i = 0; i < 8; i++)
                Vs[ws][oct * 8 + i][kp] = (unsigned)pa[i] | ((unsigned)pb[i] << 16);
        }
        // prefetch NEXT V tile: a full iteration of QK^T+softmax+PV covers it
        if (k0 + 64 < ks + KCHUNK) {
            va = *(const uint4*)(vbase + (size_t)(k0 + 64) * DMODEL);
            vb = *(const uint4*)(vbase + (size_t)(k0 + 64) * DMODEL + DMODEL);
        }
        // current mask words (4 q-rows x 64 k) — issue before QK^T MFMAs
        unsigned long long mw[4];
        #pragma unroll
        for (int reg = 0; reg < 4; reg++)
            mw[reg] = mbase[(size_t)reg * MWORDS + (k0 >> 6)];

        f4 sacc[4];
        #pragma unroll
        for (int nt = 0; nt < 4; nt++) {
            const bf16_t* krow = K + base + (size_t)(k0 + nt * 16 + l15) * DMODEL + quad * 8;
            f4 zz2 = {0.f, 0.f, 0.f, 0.f};
            zz2 = MFMA(qf0, ldfrag(krow), zz2);
            zz2 = MFMA(qf1, ldfrag(krow + 32), zz2);
            sacc[nt] = zz2;
        }

        #pragma unroll
        for (int reg = 0; reg < 4; reg++) {
            // bit (nt*16 + l15) of mw[reg] masks column k0+nt*16+l15
            const unsigned mlo = ((unsigned)mw[reg]) >> l15;
            const unsigned mhi = ((unsigned)(mw[reg] >> 32)) >> l15;
            float sv[4];
            sv[0] = (mlo & 1u)       ? sacc[0][reg] : -1.0e9f;
            sv[1] = (mlo & 0x10000u) ? sacc[1][reg] : -1.0e9f;
            sv[2] = (mhi & 1u)       ? sacc[2][reg] : -1.0e9f;
            sv[3] = (mhi & 0x10000u) ? sacc[3][reg] : -1.0e9f;

            float mx = fmaxf(fmaxf(sv[0], sv[1]), fmaxf(sv[2], sv[3]));
            mx = fmaxf(mx, __shfl_xor(mx, 1, 16));
            mx = fmaxf(mx, __shfl_xor(mx, 2, 16));
            mx = fmaxf(mx, __shfl_xor(mx, 4, 16));
            mx = fmaxf(mx, __shfl_xor(mx, 8, 16));

            const float m_new = fmaxf(m_run[reg], mx);
            const float alpha = __expf(m_run[reg] - m_new);
            float p[4];
            float rs = 0.f;
            #pragma unroll
            for (int nt = 0; nt < 4; nt++) {
                p[nt] = __expf(sv[nt] - m_new);
                rs += p[nt];
            }
            rs += __shfl_xor(rs, 1, 16);
            rs += __shfl_xor(rs, 2, 16);
            rs += __shfl_xor(rs, 4, 16);
            rs += __shfl_xor(rs, 8, 16);

            l_run[reg] = l_run[reg] * alpha + rs;
            m_run[reg] = m_new;
            #pragma unroll
            for (int dt = 0; dt < 4; dt++) oacc[dt][reg] *= alpha;

            // write this reg-row of P immediately (keeps p[] liveness at 4)
            #pragma unroll
            for (int nt = 0; nt < 4; nt++) {
                const float mine  = p[nt];
                const float other = __shfl_xor(mine, 1, 16);
                if ((lane & 1) == 0)
                    Ps[w][quad * 4 + reg][nt * 8 + (l15 >> 1)] = pack2(mine, other);
            }
        }
        __syncthreads();

        #pragma unroll
        for (int kt = 0; kt < 2; kt++) {
            union { uint4 u; s8 s; } pf;
            pf.u = *(const uint4*)&Ps[w][l15][kt * 16 + quad * 4];
            #pragma unroll
            for (int dt = 0; dt < 4; dt++) {
                union { uint4 u; s8 s; } vf;
                vf.u = *(const uint4*)&Vs[ws][dt * 16 + l15][kt * 16 + quad * 4];
                oacc[dt] = MFMA(pf.s, vf.s, oacc[dt]);
            }
        }
    }

    // ---- merge the two K-half partials through LDS ----
    // exchange (m, l): values are uniform over l15 within a (quad, reg) row
    if (l15 == 0) {
        #pragma unroll
        for (int reg = 0; reg < 4; reg++) {
            Msh[w][quad * 4 + reg] = m_run[reg];
            Lsh[w][quad * 4 + reg] = l_run[reg];
        }
    }
    __syncthreads();   // Msh/Lsh visible; all Ps/Vs reads complete (alias below)

    float scale[4];
    #pragma unroll
    for (int reg = 0; reg < 4; reg++) {
        const float m_o = Msh[w ^ 4][quad * 4 + reg];
        const float l_o = Lsh[w ^ 4][quad * 4 + reg];
        const float m_t = fmaxf(m_run[reg], m_o);
        const float w_s = __expf(m_run[reg] - m_t);
        const float w_o = __expf(m_o - m_t);
        const float l_t = l_run[reg] * w_s + l_o * w_o;   // same value on both waves
        scale[reg] = w_s / l_t;
    }
    #pragma unroll
    for (int dt = 0; dt < 4; dt++)
        #pragma unroll
        for (int reg = 0; reg < 4; reg++)
            oacc[dt][reg] *= scale[reg];

    // group 1 deposits its scaled O into LDS (aliases Ps; stride 66 -> 2-way max)
    float (*Osh)[16][66] = (float (*)[16][66])Ps;
    if (ws == 1) {
        #pragma unroll
        for (int dt = 0; dt < 4; dt++)
            #pragma unroll
            for (int reg = 0; reg < 4; reg++)
                Osh[wq][quad * 4 + reg][dt * 16 + l15] = oacc[dt][reg];
    }
    __syncthreads();

    if (ws == 0) {
        #pragma unroll
        for (int reg = 0; reg < 4; reg++) {
            const size_t row = q0 + wq * 16 + quad * 4 + reg;
            #pragma unroll
            for (int dt = 0; dt < 4; dt++) {
                const float val = oacc[dt][reg] + Osh[wq][quad * 4 + reg][dt * 16 + l15];
                O[base + row * DMODEL + dt * 16 + l15] = f2bf(val);
            }
        }
    }
}

// ---------------------------------------------------------------------------
extern "C" void kernel_launch(void* const* d_in, const int* in_sizes, int n_in,
                              void* d_out, int out_size, void* d_ws, size_t ws_size,
                              hipStream_t stream)
{
    const float* q    = (const float*)d_in[0];
    const float* k    = (const float*)d_in[1];
    const float* v    = (const float*)d_in[2];
    const int*   mask = (const int*)  d_in[3];
    const float* Wq   = (const float*)d_in[4];
    const float* bq   = (const float*)d_in[5];
    const float* Wk   = (const float*)d_in[6];
    const float* bk   = (const float*)d_in[7];
    const float* Wv   = (const float*)d_in[8];
    const float* bv   = (const float*)d_in[9];
    const float* Wo   = (const float*)d_in[10];
    const float* bo   = (const float*)d_in[11];
    float* out = (float*)d_out;

    // workspace: 4 bf16 planes (25.2 MB) + 4 bf16 weights (4.7 MB) + mbits (1 MB)
    bf16_t* wsb = (bf16_t*)d_ws;
    const size_t plane = (size_t)MROWS * DMODEL;   // 3,145,728
    bf16_t* Qp  = wsb;
    bf16_t* Kp  = wsb + plane;
    bf16_t* Vp  = wsb + 2 * plane;
    bf16_t* Ctx = wsb + 3 * plane;
    bf16_t* Wqb = wsb + 4 * plane;
    bf16_t* Wkb = Wqb + WELEM;
    bf16_t* Wvb = Wkb + WELEM;
    bf16_t* Wob = Wvb + WELEM;
    unsigned long long* mbits = (unsigned long long*)(Wob + WELEM);

    cvt_weights<<<dim3(WELEM / 1024, 4), 256, 0, stream>>>(Wq, Wk, Wv, Wo, Wqb);
    mask_to_bits<<<dim3((BB * SS * SS) / 256), 256, 0, stream>>>(mask, mbits);

    // fused Q/K/V projections (Q pre-scaled by 1/8): grid (6, 32, 3)
    gemm_tiled<float, bf16_t><<<dim3(DMODEL / 128, MROWS / 128, 3), 256, 0, stream>>>(
        q, k, v, Wqb, Wkb, Wvb, bq, bk, bv, Qp, Kp, Vp, 0.125f, 1.0f, 1.0f);

    // in-block K-split flash attention: grid (32, 12, 2), 512 thr
    attn_mfma<<<dim3(SS / 64, NHEAD, BB), 512, 0, stream>>>(Qp, Kp, Vp, mbits, Ctx);

    // output projection: grid (6, 32, 1)
    gemm_tiled<bf16_t, float><<<dim3(DMODEL / 128, MROWS / 128, 1), 256, 0, stream>>>(
        Ctx, Ctx, Ctx, Wob, Wob, Wob, bo, bo, bo, out, out, out, 1.0f, 1.0f, 1.0f);
}